// Round 16
// baseline (116.886 us; speedup 1.0000x reference)
//
#include <hip/hip_runtime.h>
#include <stdint.h>

#define N_NODES 16384
#define N_EDGES 524288
#define IN_DIM  512
#define HID     256
#define NCLS    64
#define LSTRIDE 192                // CSR slot stride (max deg ~110 for this graph)
#define NBKT    1024               // node-range buckets (16 nodes each)
#define NBBLK   256                // bucket blocks (2048 edges each)
#define ENT     4096               // entries per bucket block (2 endpoints/edge)
#define OFFSTRIDE 1032             // offbuf stride per block (1025 used, 8-pad)
#define GEMM_BLKS 256              // gemm1 blocks (64x256 tiles)

typedef __bf16 bf16x8 __attribute__((ext_vector_type(8)));
typedef float  f32x4  __attribute__((ext_vector_type(4)));
typedef unsigned int u32x4 __attribute__((ext_vector_type(4)));

// ---- bf16 helpers (RNE pack, bit-shift unpack) ----------------------------
__device__ __forceinline__ unsigned short f2bf(float f) {
    unsigned int u = __float_as_uint(f);
    u += 0x7FFFu + ((u >> 16) & 1u);
    return (unsigned short)(u >> 16);
}
__device__ __forceinline__ float bflo(unsigned int u) { return __uint_as_float(u << 16); }
__device__ __forceinline__ float bfhi(unsigned int u) { return __uint_as_float(u & 0xFFFF0000u); }

// 8 bf16 from a uint4: weighted-accumulate / plain-accumulate into float[8].
__device__ __forceinline__ void fma8(float* a, uint4 u, float w) {
    a[0] = fmaf(w, bflo(u.x), a[0]); a[1] = fmaf(w, bfhi(u.x), a[1]);
    a[2] = fmaf(w, bflo(u.y), a[2]); a[3] = fmaf(w, bfhi(u.y), a[3]);
    a[4] = fmaf(w, bflo(u.z), a[4]); a[5] = fmaf(w, bfhi(u.z), a[5]);
    a[6] = fmaf(w, bflo(u.w), a[6]); a[7] = fmaf(w, bfhi(u.w), a[7]);
}
__device__ __forceinline__ void add8(float* a, uint4 u) {
    a[0] += bflo(u.x); a[1] += bfhi(u.x);
    a[2] += bflo(u.y); a[3] += bfhi(u.y);
    a[4] += bflo(u.z); a[5] += bfhi(u.z);
    a[6] += bflo(u.w); a[7] += bfhi(u.w);
}

// ---------------------------------------------------------------------------
// Bucket-sort body: 2048 edges/block. LDS counting sort by bucket, then
// COALESCED write-out (zero scattered global stores). Emits per-block sorted
// entries gbuf[blk][4096] + exclusive offsets offbuf[blk][0..1024]. Run order
// within a bucket is racy, but the consumer bitmap-ORs -> deterministic.
__device__ __forceinline__ void bucket_body(
    int blk, const void* __restrict__ ep, unsigned int* __restrict__ offbuf,
    unsigned int* __restrict__ gbuf, char* smem) {
    unsigned int* lcnt   = (unsigned int*)smem;            //  4 KiB
    unsigned int* loff   = lcnt + NBKT;                    //  4 KiB
    unsigned int* sorted = loff + NBKT;                    // 16 KiB
    unsigned int* wsum   = sorted + ENT;                   // 16 B
    int* sflag = (int*)(wsum + 4);
    const int tid = threadIdx.x;
    if (tid == 0) {                       // int64-vs-int32 edge layout detect
        const int* p = (const int*)ep;
        int odd = 1;
        for (int k = 0; k < 64; ++k)
            if (p[2 * k + 1] != 0) odd = 0;
        *sflag = odd;
    }
    #pragma unroll
    for (int q = 0; q < 4; ++q) lcnt[tid + q * 256] = 0;
    __syncthreads();

    const int e0 = blk * 2048 + tid;
    int s[8], d[8];
    if (*sflag) {
        const long long* p = (const long long*)ep;
        #pragma unroll
        for (int q = 0; q < 8; ++q) {
            s[q] = (int)p[e0 + q * 256];
            d[q] = (int)p[N_EDGES + e0 + q * 256];
        }
    } else {
        const int* p = (const int*)ep;
        #pragma unroll
        for (int q = 0; q < 8; ++q) {
            s[q] = p[e0 + q * 256];
            d[q] = p[N_EDGES + e0 + q * 256];
        }
    }
    unsigned int meta[16];                    // bkt(10b) | slot(<<10)
    #pragma unroll
    for (int q = 0; q < 8; ++q) {
        int b0 = s[q] >> 4, b1 = d[q] >> 4;
        unsigned int sl0 = atomicAdd(&lcnt[b0], 1u);
        unsigned int sl1 = atomicAdd(&lcnt[b1], 1u);
        meta[2 * q]     = (unsigned int)b0 | (sl0 << 10);
        meta[2 * q + 1] = (unsigned int)b1 | (sl1 << 10);
    }
    __syncthreads();

    // block-wide exclusive prefix sum of lcnt[1024] (4 counters/thread)
    const int lane = tid & 63, wv = tid >> 6;
    unsigned int c0 = lcnt[4 * tid], c1 = lcnt[4 * tid + 1];
    unsigned int c2 = lcnt[4 * tid + 2], c3 = lcnt[4 * tid + 3];
    unsigned int p1 = c0 + c1, p2 = p1 + c2, tot = p2 + c3;
    unsigned int inc = tot;
    #pragma unroll
    for (int dd = 1; dd < 64; dd <<= 1) {
        unsigned int v = __shfl_up(inc, dd);
        if (lane >= dd) inc += v;
    }
    if (lane == 63) wsum[wv] = inc;
    __syncthreads();
    unsigned int wbase = 0;
    #pragma unroll
    for (int w = 0; w < 3; ++w)
        if (w < wv) wbase += wsum[w];
    unsigned int base = wbase + inc - tot;
    loff[4 * tid]     = base;
    loff[4 * tid + 1] = base + c0;
    loff[4 * tid + 2] = base + p1;
    loff[4 * tid + 3] = base + p2;
    {   // coalesced offset write-out
        uint4 ov;
        ov.x = base; ov.y = base + c0; ov.z = base + p1; ov.w = base + p2;
        *(uint4*)&offbuf[(size_t)blk * OFFSTRIDE + 4 * tid] = ov;
        if (tid == 255) offbuf[(size_t)blk * OFFSTRIDE + 1024] = ENT;
    }
    __syncthreads();

    // scatter entries into sorted[] (LDS, cheap)
    #pragma unroll
    for (int q = 0; q < 8; ++q) {
        unsigned int m0 = meta[2 * q];
        sorted[loff[m0 & 1023u] + (m0 >> 10)] =
            ((unsigned int)(s[q] & 15) << 14) | (unsigned int)d[q];
        unsigned int m1 = meta[2 * q + 1];
        sorted[loff[m1 & 1023u] + (m1 >> 10)] =
            ((unsigned int)(d[q] & 15) << 14) | (unsigned int)s[q];
    }
    __syncthreads();

    // coalesced 16 KiB copy-out
    #pragma unroll
    for (int q = 0; q < 4; ++q)
        ((uint4*)gbuf)[(size_t)blk * (ENT / 4) + tid + q * 256] =
            ((const uint4*)sorted)[tid + q * 256];
}

// ---------------------------------------------------------------------------
// build_csr: per bucket (16 nodes), 32 KiB LDS bitmap (dedup, order-
// independent -> deterministic). Thread t consumes block-t's sorted run.
__global__ __launch_bounds__(256) void build_csr(
    const unsigned int* __restrict__ offbuf, const unsigned int* __restrict__ gbuf,
    float* __restrict__ dis, int* __restrict__ ncnt,
    unsigned short* __restrict__ lists) {
    __shared__ unsigned int bml[16 * 512];   // 32 KiB
    const int tid = threadIdx.x;
    const int bkt = blockIdx.x;
    const int node0 = bkt * 16;
    {
        const u32x4 z = {0, 0, 0, 0};
        #pragma unroll
        for (int q = 0; q < 8; ++q)
            ((u32x4*)bml)[tid + q * 256] = z;
    }
    __syncthreads();
    {   // thread t: block t's run for this bucket
        const unsigned int st = offbuf[(size_t)tid * OFFSTRIDE + bkt];
        const unsigned int en = offbuf[(size_t)tid * OFFSTRIDE + bkt + 1];
        const unsigned int* sp = gbuf + (size_t)tid * ENT;
        for (unsigned int l = st; l < en; ++l) {
            unsigned int e = sp[l];
            unsigned int local = e >> 14, nbr = e & 16383u;
            atomicOr(&bml[local * 512 + (nbr >> 5)], 1u << (nbr & 31u));
        }
    }
    __syncthreads();
    const int wid = tid >> 6, lane = tid & 63;
    for (int nn = wid; nn < 16; nn += 4) {
        const int node = node0 + nn;
        const unsigned int* row = bml + nn * 512 + lane * 8;
        unsigned int w[8];
        int c = 0;
        #pragma unroll
        for (int j = 0; j < 8; ++j) { w[j] = row[j]; c += __popc(w[j]); }
        int inc = c;
        #pragma unroll
        for (int dd = 1; dd < 64; dd <<= 1) {
            int t = __shfl_up(inc, dd);
            if (lane >= dd) inc += t;
        }
        int total = __shfl(inc, 63);
        unsigned short* dst = lists + (size_t)node * LSTRIDE + (inc - c);
        int k = 0;
        #pragma unroll
        for (int j = 0; j < 8; ++j) {
            unsigned int bits = w[j];
            int base = (lane * 8 + j) * 32;
            while (bits) {
                int b = __ffs(bits) - 1;
                bits &= bits - 1;
                dst[k++] = (unsigned short)(base + b);
            }
        }
        if (lane == 63) {
            lists[(size_t)node * LSTRIDE + total] = (unsigned short)node;  // self
            ncnt[node] = total + 1;
            dis[node] = 1.0f / sqrtf((float)(total + 1) + 1e-8f);
        }
    }
}

// ---------------------------------------------------------------------------
// Load an 8-element bf16 chunk from a K-major matrix, converting from f32 on
// the fly if needed.
template <bool F32>
__device__ __forceinline__ uint4 ld_chunk(const void* __restrict__ G,
                                          size_t row, int KD, int k0, int s) {
    if constexpr (F32) {
        const float* g = (const float*)G + row * KD + k0 + s * 8;
        float4 v0 = *(const float4*)g;
        float4 v1 = *(const float4*)(g + 4);
        uint4 w;
        w.x = (unsigned int)f2bf(v0.x) | ((unsigned int)f2bf(v0.y) << 16);
        w.y = (unsigned int)f2bf(v0.z) | ((unsigned int)f2bf(v0.w) << 16);
        w.z = (unsigned int)f2bf(v1.x) | ((unsigned int)f2bf(v1.y) << 16);
        w.w = (unsigned int)f2bf(v1.z) | ((unsigned int)f2bf(v1.w) << 16);
        return w;
    } else {
        return *(const uint4*)((const unsigned short*)G + row * KD + k0 + s * 8);
    }
}

// ---------------------------------------------------------------------------
// bf16 MFMA GEMM body: C[m][n] = bf16( scale * sum_k A[m][k]*B[n][k] ),
// scale = dis[m] (or 1 if dis==nullptr). XOR slot-swizzle LDS + next-K-tile
// register prefetch. A/B may be f32 (converted during staging).
template <int BM, int BN, int KD, int ND, bool AF32, bool BF32>
__device__ __forceinline__ void gemm_body(
    int bx, int by, const void* __restrict__ Ag, const void* __restrict__ Bg,
    unsigned short* __restrict__ Cg, const float* __restrict__ dis, char* smem) {
    constexpr int FM = BM / 32, FN = BN / 32;
    constexpr int NK = KD / 64;
    unsigned short* Asm = (unsigned short*)smem;             // BM*64*2 bytes
    unsigned short* Bsm = (unsigned short*)smem + BM * 64;   // BN*64*2 bytes
    const int tid = threadIdx.x;
    const int lane = tid & 63;
    const int wid = tid >> 6;
    const int wm = wid >> 1, wn = wid & 1;
    const int m0 = bx * BM, n0 = by * BN;

    uint4 ra[BM / 32], rb[BN / 32];
    #pragma unroll
    for (int q = 0; q < BM / 32; ++q) {
        int cch = tid + 256 * q, r = cch >> 3, s = cch & 7;
        ra[q] = ld_chunk<AF32>(Ag, (size_t)(m0 + r), KD, 0, s);
    }
    #pragma unroll
    for (int q = 0; q < BN / 32; ++q) {
        int cch = tid + 256 * q, r = cch >> 3, s = cch & 7;
        rb[q] = ld_chunk<BF32>(Bg, (size_t)(n0 + r), KD, 0, s);
    }

    f32x4 acc[FM][FN] = {};

    for (int kt = 0; kt < NK; ++kt) {
        __syncthreads();
        #pragma unroll
        for (int q = 0; q < BM / 32; ++q) {
            int cch = tid + 256 * q, r = cch >> 3, s = cch & 7;
            *(uint4*)((char*)Asm + r * 128 + ((s ^ (r & 7)) << 4)) = ra[q];
        }
        #pragma unroll
        for (int q = 0; q < BN / 32; ++q) {
            int cch = tid + 256 * q, r = cch >> 3, s = cch & 7;
            *(uint4*)((char*)Bsm + r * 128 + ((s ^ (r & 7)) << 4)) = rb[q];
        }
        __syncthreads();
        if (kt + 1 < NK) {
            int k0 = (kt + 1) * 64;
            #pragma unroll
            for (int q = 0; q < BM / 32; ++q) {
                int cch = tid + 256 * q, r = cch >> 3, s = cch & 7;
                ra[q] = ld_chunk<AF32>(Ag, (size_t)(m0 + r), KD, k0, s);
            }
            #pragma unroll
            for (int q = 0; q < BN / 32; ++q) {
                int cch = tid + 256 * q, r = cch >> 3, s = cch & 7;
                rb[q] = ld_chunk<BF32>(Bg, (size_t)(n0 + r), KD, k0, s);
            }
        }
        #pragma unroll
        for (int ks = 0; ks < 2; ++ks) {
            bf16x8 af[FM], bg[FN];
            #pragma unroll
            for (int i = 0; i < FM; ++i) {
                int row = wm * (BM / 2) + i * 16 + (lane & 15);
                int slot = (ks * 4 + (lane >> 4)) ^ (row & 7);
                af[i] = *(const bf16x8*)((const char*)Asm + row * 128 + slot * 16);
            }
            #pragma unroll
            for (int j = 0; j < FN; ++j) {
                int row = wn * (BN / 2) + j * 16 + (lane & 15);
                int slot = (ks * 4 + (lane >> 4)) ^ (row & 7);
                bg[j] = *(const bf16x8*)((const char*)Bsm + row * 128 + slot * 16);
            }
            #pragma unroll
            for (int i = 0; i < FM; ++i)
                #pragma unroll
                for (int j = 0; j < FN; ++j)
                    acc[i][j] = __builtin_amdgcn_mfma_f32_16x16x32_bf16(af[i], bg[j], acc[i][j], 0, 0, 0);
        }
    }

    // C/D layout: col = lane&15, row = (lane>>4)*4 + e
    #pragma unroll
    for (int i = 0; i < FM; ++i) {
        #pragma unroll
        for (int e = 0; e < 4; ++e) {
            int row = m0 + wm * (BM / 2) + i * 16 + ((lane >> 4) << 2) + e;
            float dm = dis ? dis[row] : 1.0f;
            #pragma unroll
            for (int j = 0; j < FN; ++j) {
                int col = n0 + wn * (BN / 2) + j * 16 + (lane & 15);
                Cg[(size_t)row * ND + col] = f2bf(acc[i][j][e] * dm);
            }
        }
    }
}

// ---------------------------------------------------------------------------
// k1: blocks [0,256) run gemm1 with 64x256 tiles (BN = full HID -> X f32 is
// read from HBM exactly ONCE: 32 MB, halving k1's memory floor vs BN=128);
// blocks [256,512) run the LDS counting-sort bucketing. Independent work.
__global__ __launch_bounds__(256) void bucket_gemm(
    const float* __restrict__ X, const float* __restrict__ W1,
    unsigned short* __restrict__ Y, const void* __restrict__ ep,
    unsigned int* __restrict__ offbuf, unsigned int* __restrict__ gbuf) {
    __shared__ __align__(16) char smem[(64 + 256) * 64 * 2];   // 40 KiB
    if (blockIdx.x < GEMM_BLKS) {
        gemm_body<64, 256, IN_DIM, HID, true, true>(
            blockIdx.x, 0, X, W1, Y, nullptr, smem);
    } else {
        bucket_body(blockIdx.x - GEMM_BLKS, ep, offbuf, gbuf, smem);
    }
}

// gemm2: H1 (bf16) x W2 (f32) -> Z bf16, scaled by dis[row]. BM=64 -> 256
// blocks = 1 block/CU (BM=128 left half the CUs idle).
__global__ __launch_bounds__(256) void gemm2_k(
    const unsigned short* __restrict__ H1, const float* __restrict__ W2,
    unsigned short* __restrict__ Z, const float* __restrict__ dis) {
    __shared__ __align__(16) char smem[(64 + 64) * 64 * 2];
    gemm_body<64, 64, HID, NCLS, false, true>(blockIdx.x, 0, H1, W2, Z, dis, smem);
}

// ---------------------------------------------------------------------------
// H1[i] = bf16( relu( dis_i * sum_j dis_j * Y[j] + b1 ) ), Y unscaled.
// XCD-split feature halves (bid&7 -> XCD). 4 waves/block, one (node,fh) per
// wave. Quarter-wave per neighbor (16 lanes x dwordx4 = 256 B row-half);
// software-pipelined. NO __syncthreads: staging is wave-private (sld[wid]
// written and read only by wave wid) — barrier only convoyed unequal waves.
__global__ __launch_bounds__(256) void spmm_hid(
    const int* __restrict__ ncnt, const unsigned short* __restrict__ lists,
    const float* __restrict__ dis, const unsigned short* __restrict__ Yp,
    const float* __restrict__ bias, unsigned short* __restrict__ H1) {
    const int bid = blockIdx.x;
    const int r = bid & 7;
    const int fh = r >> 2;                   // feature half
    const int wid = threadIdx.x >> 6, lane = threadIdx.x & 63;
    const int i = (bid >> 3) * 16 + (r & 3) * 4 + wid;

    __shared__ uint2 sld[4][LSTRIDE];        // {dis_j bits, byte offset j<<9}
    const int n = min(ncnt[i], LSTRIDE);
    for (int l = lane; l < n; l += 64) {
        int j = lists[(size_t)i * LSTRIDE + l];
        uint2 m;
        m.x = __float_as_uint(dis[j]);
        m.y = (unsigned int)j << 9;
        sld[wid][l] = m;
    }
    // no barrier: wave-private LDS slice, in-wave lgkmcnt ordering suffices

    const int qw = lane >> 4, p = lane & 15;
    const char* Ybase = (const char*)Yp + fh * 256 + p * 16;
    const uint2* slw = sld[wid];
    float acc[8] = {}, acc2[8] = {};
    int l = 0;
    const int nmain = n & ~7;
    if (nmain >= 8) {
        uint2 m0 = slw[qw];
        uint2 m1 = slw[4 + qw];
        uint4 u0 = *(const uint4*)(Ybase + m0.y);
        uint4 u1 = *(const uint4*)(Ybase + m1.y);
        float w0 = __uint_as_float(m0.x), w1 = __uint_as_float(m1.x);
        #pragma unroll 2
        for (l = 8; l < nmain; l += 8) {
            uint2 t0 = slw[l + qw];
            uint2 t1 = slw[l + 4 + qw];
            uint4 v0 = *(const uint4*)(Ybase + t0.y);   // prefetch next group
            uint4 v1 = *(const uint4*)(Ybase + t1.y);
            fma8(acc, u0, w0);                          // consume current
            fma8(acc2, u1, w1);
            u0 = v0; u1 = v1;
            w0 = __uint_as_float(t0.x); w1 = __uint_as_float(t1.x);
        }
        fma8(acc, u0, w0);
        fma8(acc2, u1, w1);
        l = nmain;
    }
    for (; l < n; l += 4) {
        if (l + qw < n) {
            uint2 m = slw[l + qw];
            uint4 u = *(const uint4*)(Ybase + m.y);
            fma8(acc, u, __uint_as_float(m.x));
        }
    }
    #pragma unroll
    for (int k = 0; k < 8; ++k) {
        acc[k] += acc2[k];
        acc[k] += __shfl_xor(acc[k], 16);
        acc[k] += __shfl_xor(acc[k], 32);
    }
    if (qw == 0) {
        float di = dis[i];
        float4 b0 = *(const float4*)&bias[fh * 128 + p * 8];
        float4 b1 = *(const float4*)&bias[fh * 128 + p * 8 + 4];
        float v0 = fmaxf(fmaf(di, acc[0], b0.x), 0.0f);
        float v1 = fmaxf(fmaf(di, acc[1], b0.y), 0.0f);
        float v2 = fmaxf(fmaf(di, acc[2], b0.z), 0.0f);
        float v3 = fmaxf(fmaf(di, acc[3], b0.w), 0.0f);
        float v4 = fmaxf(fmaf(di, acc[4], b1.x), 0.0f);
        float v5 = fmaxf(fmaf(di, acc[5], b1.y), 0.0f);
        float v6 = fmaxf(fmaf(di, acc[6], b1.z), 0.0f);
        float v7 = fmaxf(fmaf(di, acc[7], b1.w), 0.0f);
        u32x4 o;
        o.x = (unsigned int)f2bf(v0) | ((unsigned int)f2bf(v1) << 16);
        o.y = (unsigned int)f2bf(v2) | ((unsigned int)f2bf(v3) << 16);
        o.z = (unsigned int)f2bf(v4) | ((unsigned int)f2bf(v5) << 16);
        o.w = (unsigned int)f2bf(v6) | ((unsigned int)f2bf(v7) << 16);
        __builtin_nontemporal_store(o, (u32x4*)&H1[(size_t)i * 256 + fh * 128 + p * 8]);
    }
}

// ---------------------------------------------------------------------------
// out[i] = dis_i * sum_j Z'[j] + b2, Z' pre-scaled by dis_j (gemm2 epilogue).
// 4 waves/block, one node per wave; 8-lane groups x dwordx4 = 128 B full row.
// Software-pipelined; no barrier (wave-private staging).
__global__ __launch_bounds__(256) void spmm_out(
    const int* __restrict__ ncnt, const unsigned short* __restrict__ lists,
    const float* __restrict__ dis, const unsigned short* __restrict__ Zp,
    const float* __restrict__ bias, float* __restrict__ out) {
    const int wid = threadIdx.x >> 6, lane = threadIdx.x & 63;
    const int i = blockIdx.x * 4 + wid;
    __shared__ unsigned int sl[4][LSTRIDE];
    const int n = min(ncnt[i], LSTRIDE);
    for (int l = lane; l < n; l += 64)
        sl[wid][l] = (unsigned int)lists[(size_t)i * LSTRIDE + l] << 7;
    // no barrier: wave-private LDS slice

    const int g = lane >> 3, p = lane & 7;
    const char* Zbase = (const char*)Zp + p * 16;
    const unsigned int* slw = sl[wid];
    float acc[8] = {}, acc2[8] = {};
    int l = 0;
    const int nmain = n & ~15;
    if (nmain >= 16) {
        uint4 u0 = *(const uint4*)(Zbase + slw[g]);
        uint4 u1 = *(const uint4*)(Zbase + slw[8 + g]);
        #pragma unroll 2
        for (l = 16; l < nmain; l += 16) {
            uint4 v0 = *(const uint4*)(Zbase + slw[l + g]);
            uint4 v1 = *(const uint4*)(Zbase + slw[l + 8 + g]);
            add8(acc, u0);
            add8(acc2, u1);
            u0 = v0; u1 = v1;
        }
        add8(acc, u0);
        add8(acc2, u1);
        l = nmain;
    }
    for (; l < n; l += 8) {
        if (l + g < n) {
            uint4 u = *(const uint4*)(Zbase + slw[l + g]);
            add8(acc, u);
        }
    }
    #pragma unroll
    for (int k = 0; k < 8; ++k) {
        acc[k] += acc2[k];
        acc[k] += __shfl_xor(acc[k], 8);
        acc[k] += __shfl_xor(acc[k], 16);
        acc[k] += __shfl_xor(acc[k], 32);
    }
    if (lane < 8) {
        float di = dis[i];
        float4 b0 = *(const float4*)&bias[p * 8];
        float4 b1 = *(const float4*)&bias[p * 8 + 4];
        f32x4 o0, o1;
        o0.x = fmaf(di, acc[0], b0.x); o0.y = fmaf(di, acc[1], b0.y);
        o0.z = fmaf(di, acc[2], b0.z); o0.w = fmaf(di, acc[3], b0.w);
        o1.x = fmaf(di, acc[4], b1.x); o1.y = fmaf(di, acc[5], b1.y);
        o1.z = fmaf(di, acc[6], b1.z); o1.w = fmaf(di, acc[7], b1.w);
        float* op = &out[(size_t)i * 64 + p * 8];
        __builtin_nontemporal_store(o0, (f32x4*)op);
        __builtin_nontemporal_store(o1, (f32x4*)(op + 4));
    }
}

// ---------------------------------------------------------------------------
extern "C" void kernel_launch(void* const* d_in, const int* in_sizes, int n_in,
                              void* d_out, int out_size, void* d_ws, size_t ws_size,
                              hipStream_t stream) {
    const float* X  = (const float*)d_in[0];
    const void*  EI = d_in[1];
    const float* W1 = (const float*)d_in[2];
    const float* b1 = (const float*)d_in[3];
    const float* W2 = (const float*)d_in[4];
    const float* b2 = (const float*)d_in[5];
    float* out = (float*)d_out;

    char* ws = (char*)d_ws;
    char* p = ws;
    unsigned int* offbuf = (unsigned int*)p;     p += (size_t)NBBLK * OFFSTRIDE * 4;    // ~1 MiB
    unsigned int* gbuf   = (unsigned int*)p;     p += (size_t)NBBLK * ENT * 4;          //  4 MiB
    float* dis = (float*)p;                      p += (size_t)N_NODES * 4;
    int* ncnt = (int*)p;                         p += (size_t)N_NODES * 4;
    unsigned short* lists = (unsigned short*)p;  p += (size_t)N_NODES * LSTRIDE * 2;    //  6 MiB
    unsigned short* Y   = (unsigned short*)p;    p += (size_t)N_NODES * HID * 2;        //  8 MiB
    unsigned short* H1  = (unsigned short*)p;    p += (size_t)N_NODES * HID * 2;        //  8 MiB
    unsigned short* Z   = (unsigned short*)p;    p += (size_t)N_NODES * NCLS * 2;       //  2 MiB

    // k1: gemm1 (Y = bf16(X @ W1^T), 64x256 tiles, X read once) || bucketing
    bucket_gemm<<<GEMM_BLKS + NBBLK, 256, 0, stream>>>(X, W1, Y, EI, offbuf, gbuf);
    // k2: LDS-bitmap dedup -> CSR lists + dis
    build_csr<<<NBKT, 256, 0, stream>>>(offbuf, gbuf, dis, ncnt, lists);
    // k3: H1 = bf16( relu(dis_i * sum dis_j Y_j + b1) )   [XCD-split gather]
    spmm_hid<<<2 * N_NODES / 4, 256, 0, stream>>>(ncnt, lists, dis, Y, b1, H1);
    // k4: Z = bf16( dis_row .* (H1 @ W2^T) )
    gemm2_k<<<N_NODES / 64, 256, 0, stream>>>(H1, W2, Z, dis);
    // k5: out = dis_i * sum Z'_j + b2   (f32)
    spmm_out<<<N_NODES / 4, 256, 0, stream>>>(ncnt, lists, dis, Z, b2, out);
}

// Round 17
// 99.111 us; speedup vs baseline: 1.1793x; 1.1793x over previous
//
#include <hip/hip_runtime.h>
#include <stdint.h>

#define N_NODES 16384
#define N_EDGES 524288
#define IN_DIM  512
#define HID     256
#define NCLS    64
#define LSTRIDE 192                // CSR slot stride (max deg ~110 for this graph)
#define NBKT    1024               // node-range buckets (16 nodes each)
#define NBBLK   256                // bucket blocks (2048 edges each)
#define ENT     4096               // entries per bucket block (2 endpoints/edge)
#define OFFSTRIDE 1032             // offbuf stride per block (1025 used, 8-pad)
#define GEMM_BLKS 256              // gemm1 blocks (128x128 tiles)

typedef __bf16 bf16x8 __attribute__((ext_vector_type(8)));
typedef float  f32x4  __attribute__((ext_vector_type(4)));
typedef unsigned int u32x4 __attribute__((ext_vector_type(4)));

// ---- bf16 helpers (RNE pack, bit-shift unpack) ----------------------------
__device__ __forceinline__ unsigned short f2bf(float f) {
    unsigned int u = __float_as_uint(f);
    u += 0x7FFFu + ((u >> 16) & 1u);
    return (unsigned short)(u >> 16);
}
__device__ __forceinline__ float bflo(unsigned int u) { return __uint_as_float(u << 16); }
__device__ __forceinline__ float bfhi(unsigned int u) { return __uint_as_float(u & 0xFFFF0000u); }

// 8 bf16 from a uint4: weighted-accumulate / plain-accumulate into float[8].
__device__ __forceinline__ void fma8(float* a, uint4 u, float w) {
    a[0] = fmaf(w, bflo(u.x), a[0]); a[1] = fmaf(w, bfhi(u.x), a[1]);
    a[2] = fmaf(w, bflo(u.y), a[2]); a[3] = fmaf(w, bfhi(u.y), a[3]);
    a[4] = fmaf(w, bflo(u.z), a[4]); a[5] = fmaf(w, bfhi(u.z), a[5]);
    a[6] = fmaf(w, bflo(u.w), a[6]); a[7] = fmaf(w, bfhi(u.w), a[7]);
}
__device__ __forceinline__ void add8(float* a, uint4 u) {
    a[0] += bflo(u.x); a[1] += bfhi(u.x);
    a[2] += bflo(u.y); a[3] += bfhi(u.y);
    a[4] += bflo(u.z); a[5] += bfhi(u.z);
    a[6] += bflo(u.w); a[7] += bfhi(u.w);
}

// ---------------------------------------------------------------------------
// Bucket-sort body: 2048 edges/block. LDS counting sort by bucket, then
// COALESCED write-out (zero scattered global stores). Emits per-block sorted
// entries gbuf[blk][4096] + exclusive offsets offbuf[blk][0..1024]. Run order
// within a bucket is racy, but the consumer bitmap-ORs -> deterministic.
__device__ __forceinline__ void bucket_body(
    int blk, const void* __restrict__ ep, unsigned int* __restrict__ offbuf,
    unsigned int* __restrict__ gbuf, char* smem) {
    unsigned int* lcnt   = (unsigned int*)smem;            //  4 KiB
    unsigned int* loff   = lcnt + NBKT;                    //  4 KiB
    unsigned int* sorted = loff + NBKT;                    // 16 KiB
    unsigned int* wsum   = sorted + ENT;                   // 16 B
    int* sflag = (int*)(wsum + 4);
    const int tid = threadIdx.x;
    if (tid == 0) {                       // int64-vs-int32 edge layout detect
        const int* p = (const int*)ep;
        int odd = 1;
        for (int k = 0; k < 64; ++k)
            if (p[2 * k + 1] != 0) odd = 0;
        *sflag = odd;
    }
    #pragma unroll
    for (int q = 0; q < 4; ++q) lcnt[tid + q * 256] = 0;
    __syncthreads();

    const int e0 = blk * 2048 + tid;
    int s[8], d[8];
    if (*sflag) {
        const long long* p = (const long long*)ep;
        #pragma unroll
        for (int q = 0; q < 8; ++q) {
            s[q] = (int)p[e0 + q * 256];
            d[q] = (int)p[N_EDGES + e0 + q * 256];
        }
    } else {
        const int* p = (const int*)ep;
        #pragma unroll
        for (int q = 0; q < 8; ++q) {
            s[q] = p[e0 + q * 256];
            d[q] = p[N_EDGES + e0 + q * 256];
        }
    }
    unsigned int meta[16];                    // bkt(10b) | slot(<<10)
    #pragma unroll
    for (int q = 0; q < 8; ++q) {
        int b0 = s[q] >> 4, b1 = d[q] >> 4;
        unsigned int sl0 = atomicAdd(&lcnt[b0], 1u);
        unsigned int sl1 = atomicAdd(&lcnt[b1], 1u);
        meta[2 * q]     = (unsigned int)b0 | (sl0 << 10);
        meta[2 * q + 1] = (unsigned int)b1 | (sl1 << 10);
    }
    __syncthreads();

    // block-wide exclusive prefix sum of lcnt[1024] (4 counters/thread)
    const int lane = tid & 63, wv = tid >> 6;
    unsigned int c0 = lcnt[4 * tid], c1 = lcnt[4 * tid + 1];
    unsigned int c2 = lcnt[4 * tid + 2], c3 = lcnt[4 * tid + 3];
    unsigned int p1 = c0 + c1, p2 = p1 + c2, tot = p2 + c3;
    unsigned int inc = tot;
    #pragma unroll
    for (int dd = 1; dd < 64; dd <<= 1) {
        unsigned int v = __shfl_up(inc, dd);
        if (lane >= dd) inc += v;
    }
    if (lane == 63) wsum[wv] = inc;
    __syncthreads();
    unsigned int wbase = 0;
    #pragma unroll
    for (int w = 0; w < 3; ++w)
        if (w < wv) wbase += wsum[w];
    unsigned int base = wbase + inc - tot;
    loff[4 * tid]     = base;
    loff[4 * tid + 1] = base + c0;
    loff[4 * tid + 2] = base + p1;
    loff[4 * tid + 3] = base + p2;
    {   // coalesced offset write-out
        uint4 ov;
        ov.x = base; ov.y = base + c0; ov.z = base + p1; ov.w = base + p2;
        *(uint4*)&offbuf[(size_t)blk * OFFSTRIDE + 4 * tid] = ov;
        if (tid == 255) offbuf[(size_t)blk * OFFSTRIDE + 1024] = ENT;
    }
    __syncthreads();

    // scatter entries into sorted[] (LDS, cheap)
    #pragma unroll
    for (int q = 0; q < 8; ++q) {
        unsigned int m0 = meta[2 * q];
        sorted[loff[m0 & 1023u] + (m0 >> 10)] =
            ((unsigned int)(s[q] & 15) << 14) | (unsigned int)d[q];
        unsigned int m1 = meta[2 * q + 1];
        sorted[loff[m1 & 1023u] + (m1 >> 10)] =
            ((unsigned int)(d[q] & 15) << 14) | (unsigned int)s[q];
    }
    __syncthreads();

    // coalesced 16 KiB copy-out
    #pragma unroll
    for (int q = 0; q < 4; ++q)
        ((uint4*)gbuf)[(size_t)blk * (ENT / 4) + tid + q * 256] =
            ((const uint4*)sorted)[tid + q * 256];
}

// ---------------------------------------------------------------------------
// build_csr: per bucket (16 nodes), 32 KiB LDS bitmap (dedup, order-
// independent -> deterministic). Thread t consumes block-t's sorted run.
__global__ __launch_bounds__(256) void build_csr(
    const unsigned int* __restrict__ offbuf, const unsigned int* __restrict__ gbuf,
    float* __restrict__ dis, int* __restrict__ ncnt,
    unsigned short* __restrict__ lists) {
    __shared__ unsigned int bml[16 * 512];   // 32 KiB
    const int tid = threadIdx.x;
    const int bkt = blockIdx.x;
    const int node0 = bkt * 16;
    {
        const u32x4 z = {0, 0, 0, 0};
        #pragma unroll
        for (int q = 0; q < 8; ++q)
            ((u32x4*)bml)[tid + q * 256] = z;
    }
    __syncthreads();
    {   // thread t: block t's run for this bucket
        const unsigned int st = offbuf[(size_t)tid * OFFSTRIDE + bkt];
        const unsigned int en = offbuf[(size_t)tid * OFFSTRIDE + bkt + 1];
        const unsigned int* sp = gbuf + (size_t)tid * ENT;
        for (unsigned int l = st; l < en; ++l) {
            unsigned int e = sp[l];
            unsigned int local = e >> 14, nbr = e & 16383u;
            atomicOr(&bml[local * 512 + (nbr >> 5)], 1u << (nbr & 31u));
        }
    }
    __syncthreads();
    const int wid = tid >> 6, lane = tid & 63;
    for (int nn = wid; nn < 16; nn += 4) {
        const int node = node0 + nn;
        const unsigned int* row = bml + nn * 512 + lane * 8;
        unsigned int w[8];
        int c = 0;
        #pragma unroll
        for (int j = 0; j < 8; ++j) { w[j] = row[j]; c += __popc(w[j]); }
        int inc = c;
        #pragma unroll
        for (int dd = 1; dd < 64; dd <<= 1) {
            int t = __shfl_up(inc, dd);
            if (lane >= dd) inc += t;
        }
        int total = __shfl(inc, 63);
        unsigned short* dst = lists + (size_t)node * LSTRIDE + (inc - c);
        int k = 0;
        #pragma unroll
        for (int j = 0; j < 8; ++j) {
            unsigned int bits = w[j];
            int base = (lane * 8 + j) * 32;
            while (bits) {
                int b = __ffs(bits) - 1;
                bits &= bits - 1;
                dst[k++] = (unsigned short)(base + b);
            }
        }
        if (lane == 63) {
            lists[(size_t)node * LSTRIDE + total] = (unsigned short)node;  // self
            ncnt[node] = total + 1;
            dis[node] = 1.0f / sqrtf((float)(total + 1) + 1e-8f);
        }
    }
}

// ---------------------------------------------------------------------------
// Load an 8-element bf16 chunk from a K-major matrix, converting from f32 on
// the fly if needed.
template <bool F32>
__device__ __forceinline__ uint4 ld_chunk(const void* __restrict__ G,
                                          size_t row, int KD, int k0, int s) {
    if constexpr (F32) {
        const float* g = (const float*)G + row * KD + k0 + s * 8;
        float4 v0 = *(const float4*)g;
        float4 v1 = *(const float4*)(g + 4);
        uint4 w;
        w.x = (unsigned int)f2bf(v0.x) | ((unsigned int)f2bf(v0.y) << 16);
        w.y = (unsigned int)f2bf(v0.z) | ((unsigned int)f2bf(v0.w) << 16);
        w.z = (unsigned int)f2bf(v1.x) | ((unsigned int)f2bf(v1.y) << 16);
        w.w = (unsigned int)f2bf(v1.z) | ((unsigned int)f2bf(v1.w) << 16);
        return w;
    } else {
        return *(const uint4*)((const unsigned short*)G + row * KD + k0 + s * 8);
    }
}

// ---------------------------------------------------------------------------
// bf16 MFMA GEMM body: C[m][n] = bf16( scale * sum_k A[m][k]*B[n][k] ),
// scale = dis[m] (or 1 if dis==nullptr). XOR slot-swizzle LDS + next-K-tile
// register prefetch. A/B may be f32 (converted during staging).
// NOTE: keep BM/BN <= 128 — 64x256 (acc 64 + prefetch 40 + frag 48 VGPR)
// spilled to scratch at VGPR_Count=108 and ran 4x slower (r16 post-mortem).
template <int BM, int BN, int KD, int ND, bool AF32, bool BF32>
__device__ __forceinline__ void gemm_body(
    int bx, int by, const void* __restrict__ Ag, const void* __restrict__ Bg,
    unsigned short* __restrict__ Cg, const float* __restrict__ dis, char* smem) {
    constexpr int FM = BM / 32, FN = BN / 32;
    constexpr int NK = KD / 64;
    unsigned short* Asm = (unsigned short*)smem;             // BM*64*2 bytes
    unsigned short* Bsm = (unsigned short*)smem + BM * 64;   // BN*64*2 bytes
    const int tid = threadIdx.x;
    const int lane = tid & 63;
    const int wid = tid >> 6;
    const int wm = wid >> 1, wn = wid & 1;
    const int m0 = bx * BM, n0 = by * BN;

    uint4 ra[BM / 32], rb[BN / 32];
    #pragma unroll
    for (int q = 0; q < BM / 32; ++q) {
        int cch = tid + 256 * q, r = cch >> 3, s = cch & 7;
        ra[q] = ld_chunk<AF32>(Ag, (size_t)(m0 + r), KD, 0, s);
    }
    #pragma unroll
    for (int q = 0; q < BN / 32; ++q) {
        int cch = tid + 256 * q, r = cch >> 3, s = cch & 7;
        rb[q] = ld_chunk<BF32>(Bg, (size_t)(n0 + r), KD, 0, s);
    }

    f32x4 acc[FM][FN] = {};

    for (int kt = 0; kt < NK; ++kt) {
        __syncthreads();
        #pragma unroll
        for (int q = 0; q < BM / 32; ++q) {
            int cch = tid + 256 * q, r = cch >> 3, s = cch & 7;
            *(uint4*)((char*)Asm + r * 128 + ((s ^ (r & 7)) << 4)) = ra[q];
        }
        #pragma unroll
        for (int q = 0; q < BN / 32; ++q) {
            int cch = tid + 256 * q, r = cch >> 3, s = cch & 7;
            *(uint4*)((char*)Bsm + r * 128 + ((s ^ (r & 7)) << 4)) = rb[q];
        }
        __syncthreads();
        if (kt + 1 < NK) {
            int k0 = (kt + 1) * 64;
            #pragma unroll
            for (int q = 0; q < BM / 32; ++q) {
                int cch = tid + 256 * q, r = cch >> 3, s = cch & 7;
                ra[q] = ld_chunk<AF32>(Ag, (size_t)(m0 + r), KD, k0, s);
            }
            #pragma unroll
            for (int q = 0; q < BN / 32; ++q) {
                int cch = tid + 256 * q, r = cch >> 3, s = cch & 7;
                rb[q] = ld_chunk<BF32>(Bg, (size_t)(n0 + r), KD, k0, s);
            }
        }
        #pragma unroll
        for (int ks = 0; ks < 2; ++ks) {
            bf16x8 af[FM], bg[FN];
            #pragma unroll
            for (int i = 0; i < FM; ++i) {
                int row = wm * (BM / 2) + i * 16 + (lane & 15);
                int slot = (ks * 4 + (lane >> 4)) ^ (row & 7);
                af[i] = *(const bf16x8*)((const char*)Asm + row * 128 + slot * 16);
            }
            #pragma unroll
            for (int j = 0; j < FN; ++j) {
                int row = wn * (BN / 2) + j * 16 + (lane & 15);
                int slot = (ks * 4 + (lane >> 4)) ^ (row & 7);
                bg[j] = *(const bf16x8*)((const char*)Bsm + row * 128 + slot * 16);
            }
            #pragma unroll
            for (int i = 0; i < FM; ++i)
                #pragma unroll
                for (int j = 0; j < FN; ++j)
                    acc[i][j] = __builtin_amdgcn_mfma_f32_16x16x32_bf16(af[i], bg[j], acc[i][j], 0, 0, 0);
        }
    }

    // C/D layout: col = lane&15, row = (lane>>4)*4 + e
    #pragma unroll
    for (int i = 0; i < FM; ++i) {
        #pragma unroll
        for (int e = 0; e < 4; ++e) {
            int row = m0 + wm * (BM / 2) + i * 16 + ((lane >> 4) << 2) + e;
            float dm = dis ? dis[row] : 1.0f;
            #pragma unroll
            for (int j = 0; j < FN; ++j) {
                int col = n0 + wn * (BN / 2) + j * 16 + (lane & 15);
                Cg[(size_t)row * ND + col] = f2bf(acc[i][j][e] * dm);
            }
        }
    }
}

// ---------------------------------------------------------------------------
// k1: blocks [0,256) run gemm1 (X f32 x W1 f32 -> Y bf16, unscaled, 128x128
// — the r14/r15 known-good config, ~13 µs, no spill);
// blocks [256,512) run the LDS counting-sort bucketing. Independent work.
__global__ __launch_bounds__(256) void bucket_gemm(
    const float* __restrict__ X, const float* __restrict__ W1,
    unsigned short* __restrict__ Y, const void* __restrict__ ep,
    unsigned int* __restrict__ offbuf, unsigned int* __restrict__ gbuf) {
    __shared__ __align__(16) char smem[(128 + 128) * 64 * 2];   // 32 KiB
    if (blockIdx.x < GEMM_BLKS) {
        int gb = blockIdx.x;
        gemm_body<128, 128, IN_DIM, HID, true, true>(
            gb & 127, gb >> 7, X, W1, Y, nullptr, smem);
    } else {
        bucket_body(blockIdx.x - GEMM_BLKS, ep, offbuf, gbuf, smem);
    }
}

// gemm2: H1 (bf16) x W2 (f32) -> Z bf16, scaled by dis[row]. BM=64 -> 256
// blocks = 1 block/CU (BM=128 left half the CUs idle).
__global__ __launch_bounds__(256) void gemm2_k(
    const unsigned short* __restrict__ H1, const float* __restrict__ W2,
    unsigned short* __restrict__ Z, const float* __restrict__ dis) {
    __shared__ __align__(16) char smem[(64 + 64) * 64 * 2];
    gemm_body<64, 64, HID, NCLS, false, true>(blockIdx.x, 0, H1, W2, Z, dis, smem);
}

// ---------------------------------------------------------------------------
// H1[i] = bf16( relu( dis_i * sum_j dis_j * Y[j] + b1 ) ), Y unscaled.
// XCD-split feature halves (bid&7 -> XCD). 4 waves/block, one (node,fh) per
// wave. Quarter-wave per neighbor (16 lanes x dwordx4 = 256 B row-half);
// software-pipelined. NO __syncthreads: staging is wave-private (sld[wid]
// written and read only by wave wid) — barrier only convoyed unequal waves.
__global__ __launch_bounds__(256) void spmm_hid(
    const int* __restrict__ ncnt, const unsigned short* __restrict__ lists,
    const float* __restrict__ dis, const unsigned short* __restrict__ Yp,
    const float* __restrict__ bias, unsigned short* __restrict__ H1) {
    const int bid = blockIdx.x;
    const int r = bid & 7;
    const int fh = r >> 2;                   // feature half
    const int wid = threadIdx.x >> 6, lane = threadIdx.x & 63;
    const int i = (bid >> 3) * 16 + (r & 3) * 4 + wid;

    __shared__ uint2 sld[4][LSTRIDE];        // {dis_j bits, byte offset j<<9}
    const int n = min(ncnt[i], LSTRIDE);
    for (int l = lane; l < n; l += 64) {
        int j = lists[(size_t)i * LSTRIDE + l];
        uint2 m;
        m.x = __float_as_uint(dis[j]);
        m.y = (unsigned int)j << 9;
        sld[wid][l] = m;
    }
    // no barrier: wave-private LDS slice, in-wave lgkmcnt ordering suffices

    const int qw = lane >> 4, p = lane & 15;
    const char* Ybase = (const char*)Yp + fh * 256 + p * 16;
    const uint2* slw = sld[wid];
    float acc[8] = {}, acc2[8] = {};
    int l = 0;
    const int nmain = n & ~7;
    if (nmain >= 8) {
        uint2 m0 = slw[qw];
        uint2 m1 = slw[4 + qw];
        uint4 u0 = *(const uint4*)(Ybase + m0.y);
        uint4 u1 = *(const uint4*)(Ybase + m1.y);
        float w0 = __uint_as_float(m0.x), w1 = __uint_as_float(m1.x);
        #pragma unroll 2
        for (l = 8; l < nmain; l += 8) {
            uint2 t0 = slw[l + qw];
            uint2 t1 = slw[l + 4 + qw];
            uint4 v0 = *(const uint4*)(Ybase + t0.y);   // prefetch next group
            uint4 v1 = *(const uint4*)(Ybase + t1.y);
            fma8(acc, u0, w0);                          // consume current
            fma8(acc2, u1, w1);
            u0 = v0; u1 = v1;
            w0 = __uint_as_float(t0.x); w1 = __uint_as_float(t1.x);
        }
        fma8(acc, u0, w0);
        fma8(acc2, u1, w1);
        l = nmain;
    }
    for (; l < n; l += 4) {
        if (l + qw < n) {
            uint2 m = slw[l + qw];
            uint4 u = *(const uint4*)(Ybase + m.y);
            fma8(acc, u, __uint_as_float(m.x));
        }
    }
    #pragma unroll
    for (int k = 0; k < 8; ++k) {
        acc[k] += acc2[k];
        acc[k] += __shfl_xor(acc[k], 16);
        acc[k] += __shfl_xor(acc[k], 32);
    }
    if (qw == 0) {
        float di = dis[i];
        float4 b0 = *(const float4*)&bias[fh * 128 + p * 8];
        float4 b1 = *(const float4*)&bias[fh * 128 + p * 8 + 4];
        float v0 = fmaxf(fmaf(di, acc[0], b0.x), 0.0f);
        float v1 = fmaxf(fmaf(di, acc[1], b0.y), 0.0f);
        float v2 = fmaxf(fmaf(di, acc[2], b0.z), 0.0f);
        float v3 = fmaxf(fmaf(di, acc[3], b0.w), 0.0f);
        float v4 = fmaxf(fmaf(di, acc[4], b1.x), 0.0f);
        float v5 = fmaxf(fmaf(di, acc[5], b1.y), 0.0f);
        float v6 = fmaxf(fmaf(di, acc[6], b1.z), 0.0f);
        float v7 = fmaxf(fmaf(di, acc[7], b1.w), 0.0f);
        u32x4 o;
        o.x = (unsigned int)f2bf(v0) | ((unsigned int)f2bf(v1) << 16);
        o.y = (unsigned int)f2bf(v2) | ((unsigned int)f2bf(v3) << 16);
        o.z = (unsigned int)f2bf(v4) | ((unsigned int)f2bf(v5) << 16);
        o.w = (unsigned int)f2bf(v6) | ((unsigned int)f2bf(v7) << 16);
        __builtin_nontemporal_store(o, (u32x4*)&H1[(size_t)i * 256 + fh * 128 + p * 8]);
    }
}

// ---------------------------------------------------------------------------
// out[i] = dis_i * sum_j Z'[j] + b2, Z' pre-scaled by dis_j (gemm2 epilogue).
// 4 waves/block, one node per wave; 8-lane groups x dwordx4 = 128 B full row.
// Software-pipelined; no barrier (wave-private staging).
__global__ __launch_bounds__(256) void spmm_out(
    const int* __restrict__ ncnt, const unsigned short* __restrict__ lists,
    const float* __restrict__ dis, const unsigned short* __restrict__ Zp,
    const float* __restrict__ bias, float* __restrict__ out) {
    const int wid = threadIdx.x >> 6, lane = threadIdx.x & 63;
    const int i = blockIdx.x * 4 + wid;
    __shared__ unsigned int sl[4][LSTRIDE];
    const int n = min(ncnt[i], LSTRIDE);
    for (int l = lane; l < n; l += 64)
        sl[wid][l] = (unsigned int)lists[(size_t)i * LSTRIDE + l] << 7;
    // no barrier: wave-private LDS slice

    const int g = lane >> 3, p = lane & 7;
    const char* Zbase = (const char*)Zp + p * 16;
    const unsigned int* slw = sl[wid];
    float acc[8] = {}, acc2[8] = {};
    int l = 0;
    const int nmain = n & ~15;
    if (nmain >= 16) {
        uint4 u0 = *(const uint4*)(Zbase + slw[g]);
        uint4 u1 = *(const uint4*)(Zbase + slw[8 + g]);
        #pragma unroll 2
        for (l = 16; l < nmain; l += 16) {
            uint4 v0 = *(const uint4*)(Zbase + slw[l + g]);
            uint4 v1 = *(const uint4*)(Zbase + slw[l + 8 + g]);
            add8(acc, u0);
            add8(acc2, u1);
            u0 = v0; u1 = v1;
        }
        add8(acc, u0);
        add8(acc2, u1);
        l = nmain;
    }
    for (; l < n; l += 8) {
        if (l + g < n) {
            uint4 u = *(const uint4*)(Zbase + slw[l + g]);
            add8(acc, u);
        }
    }
    #pragma unroll
    for (int k = 0; k < 8; ++k) {
        acc[k] += acc2[k];
        acc[k] += __shfl_xor(acc[k], 8);
        acc[k] += __shfl_xor(acc[k], 16);
        acc[k] += __shfl_xor(acc[k], 32);
    }
    if (lane < 8) {
        float di = dis[i];
        float4 b0 = *(const float4*)&bias[p * 8];
        float4 b1 = *(const float4*)&bias[p * 8 + 4];
        f32x4 o0, o1;
        o0.x = fmaf(di, acc[0], b0.x); o0.y = fmaf(di, acc[1], b0.y);
        o0.z = fmaf(di, acc[2], b0.z); o0.w = fmaf(di, acc[3], b0.w);
        o1.x = fmaf(di, acc[4], b1.x); o1.y = fmaf(di, acc[5], b1.y);
        o1.z = fmaf(di, acc[6], b1.z); o1.w = fmaf(di, acc[7], b1.w);
        float* op = &out[(size_t)i * 64 + p * 8];
        __builtin_nontemporal_store(o0, (f32x4*)op);
        __builtin_nontemporal_store(o1, (f32x4*)(op + 4));
    }
}

// ---------------------------------------------------------------------------
extern "C" void kernel_launch(void* const* d_in, const int* in_sizes, int n_in,
                              void* d_out, int out_size, void* d_ws, size_t ws_size,
                              hipStream_t stream) {
    const float* X  = (const float*)d_in[0];
    const void*  EI = d_in[1];
    const float* W1 = (const float*)d_in[2];
    const float* b1 = (const float*)d_in[3];
    const float* W2 = (const float*)d_in[4];
    const float* b2 = (const float*)d_in[5];
    float* out = (float*)d_out;

    char* ws = (char*)d_ws;
    char* p = ws;
    unsigned int* offbuf = (unsigned int*)p;     p += (size_t)NBBLK * OFFSTRIDE * 4;    // ~1 MiB
    unsigned int* gbuf   = (unsigned int*)p;     p += (size_t)NBBLK * ENT * 4;          //  4 MiB
    float* dis = (float*)p;                      p += (size_t)N_NODES * 4;
    int* ncnt = (int*)p;                         p += (size_t)N_NODES * 4;
    unsigned short* lists = (unsigned short*)p;  p += (size_t)N_NODES * LSTRIDE * 2;    //  6 MiB
    unsigned short* Y   = (unsigned short*)p;    p += (size_t)N_NODES * HID * 2;        //  8 MiB
    unsigned short* H1  = (unsigned short*)p;    p += (size_t)N_NODES * HID * 2;        //  8 MiB
    unsigned short* Z   = (unsigned short*)p;    p += (size_t)N_NODES * NCLS * 2;       //  2 MiB

    // k1: gemm1 (Y = bf16(X @ W1^T), 128x128, cvt-in-staging) || bucketing
    bucket_gemm<<<GEMM_BLKS + NBBLK, 256, 0, stream>>>(X, W1, Y, EI, offbuf, gbuf);
    // k2: LDS-bitmap dedup -> CSR lists + dis
    build_csr<<<NBKT, 256, 0, stream>>>(offbuf, gbuf, dis, ncnt, lists);
    // k3: H1 = bf16( relu(dis_i * sum dis_j Y_j + b1) )   [XCD-split gather]
    spmm_hid<<<2 * N_NODES / 4, 256, 0, stream>>>(ncnt, lists, dis, Y, b1, H1);
    // k4: Z = bf16( dis_row .* (H1 @ W2^T) )
    gemm2_k<<<N_NODES / 64, 256, 0, stream>>>(H1, W2, Z, dis);
    // k5: out = dis_i * sum Z'_j + b2   (f32)
    spmm_out<<<N_NODES / 4, 256, 0, stream>>>(ncnt, lists, dis, Z, b2, out);
}